// Round 13
// baseline (414.157 us; speedup 1.0000x reference)
//
#include <hip/hip_runtime.h>

// LIF layer: B=64, T=256, P=1024, D=1024. reference ignores prv_voltage.
// d_out = [voltage (B*T*D fp32) | spikes (B*T*D fp32)].
//
// NUMERICS LOCKED (R10): currents[row,d] =
//   (asc-p f32 single-acc sum over active p in [0,512))
// + (asc-p f32 single-acc sum over active p in [512,1024)),
// scan = f32 separate mul-then-add, >=1.0, reset-to-zero.
//
// R13: R12 hit the L2 random-gather ceiling (6.7 GB @ ~24 TB/s = 279 us).
// Move W delivery to LDS (69 TB/s): block = 32 rows x 256-col d-slice;
// 16 p-chunks of 64 staged to LDS in ASCENDING order; chunks 0-7 fold into
// accA (panel0), 8-15 into accB (panel1), accumulator carried across chunks
// -> bitwise identical to flat ascending per panel. Final accA+accB = P0+P1.
// Batched (<=4) ds_read_b128, lane-consecutive (conflict-free); masks walked
// on SALU via readfirstlane. MFMA rejected: unknown internal sum tree !=
// locked order; dataset provably knife-edged.

#define LIF_B 64
#define LIF_T 256
#define LIF_P 1024
#define LIF_D 1024
#define LIF_N ((size_t)LIF_B * LIF_T * LIF_D)

__global__ __launch_bounds__(256) void lif_currents_kernel(
    const float* __restrict__ spikes,   // (B*T, P)
    const float* __restrict__ W,        // (P, D)
    float* __restrict__ cur_out)        // (B*T, D) — voltage region of d_out
{
    __shared__ float4 wbuf[64 * 64];                 // [p_local][f4col] 64 KB
    __shared__ unsigned long long masks[32][16];     // 4 KB

    const int tid  = threadIdx.x;
    const int lane = tid & 63;
    const int wave = tid >> 6;
    const int bid  = blockIdx.x;        // ds-major: bid = ds*512 + rg
    const int ds   = bid >> 9;          // 0..3
    const int rg   = bid & 511;         // 0..511
    const int row0 = rg << 5;           // 32 rows per block
    const int dbase = ds << 8;          // 256-col slice

    // ---- Phase A: per-row per-chunk activity masks (wave handles its 8 rows)
    for (int i = 0; i < 8; ++i) {
        const int rl = (wave << 3) + i;
        const float* srow = spikes + (size_t)(row0 + rl) * LIF_P;
        #pragma unroll 4
        for (int c = 0; c < 16; ++c) {
            const float sv = srow[(c << 6) + lane];
            const unsigned long long m = __ballot(sv != 0.0f);
            if (lane == 0) masks[rl][c] = m;
        }
    }

    float4 accA[8], accB[8];
    #pragma unroll
    for (int i = 0; i < 8; ++i) {
        accA[i] = make_float4(0.f, 0.f, 0.f, 0.f);
        accB[i] = make_float4(0.f, 0.f, 0.f, 0.f);
    }

    #define LIF_ACC4(A, WV)                                                   \
        (A).x = __fadd_rn((A).x, (WV).x); (A).y = __fadd_rn((A).y, (WV).y);   \
        (A).z = __fadd_rn((A).z, (WV).z); (A).w = __fadd_rn((A).w, (WV).w);

    // stage chunk c (64 p-rows x 256 cols) into wbuf; each wave does 16 rows
    #define LIF_STAGE(C)                                                      \
    {                                                                         \
        const float* gsrc = W + ((size_t)(((C) << 6) + (wave << 4)) << 10)    \
                              + dbase + (lane << 2);                          \
        char* lbase = (char*)wbuf + ((wave << 4) << 10);                      \
        _Pragma("unroll")                                                     \
        for (int i = 0; i < 16; ++i) {                                        \
            __builtin_amdgcn_global_load_lds(                                 \
                (const __attribute__((address_space(1))) void*)(gsrc + ((size_t)i << 10)), \
                (__attribute__((address_space(3))) void*)(lbase + (i << 10)), \
                16, 0, 0);                                                    \
        }                                                                     \
    }

    // walk this wave's 8 rows for chunk C, folding into ACC (static indices)
    #define LIF_COMPUTE(C, ACC)                                               \
    {                                                                         \
        _Pragma("unroll")                                                     \
        for (int i = 0; i < 8; ++i) {                                         \
            unsigned long long m = masks[(wave << 3) + i][(C)];               \
            m = ((unsigned long long)__builtin_amdgcn_readfirstlane(          \
                     (unsigned)(m >> 32)) << 32)                              \
              | (unsigned)__builtin_amdgcn_readfirstlane((unsigned)m);        \
            while (m) {                                                       \
                const int p0 = __builtin_ctzll(m); m &= (m - 1);              \
                const float4 w0 = wbuf[(p0 << 6) | lane];                     \
                if (m) {                                                      \
                    const int p1 = __builtin_ctzll(m); m &= (m - 1);          \
                    const float4 w1 = wbuf[(p1 << 6) | lane];                 \
                    if (m) {                                                  \
                        const int p2 = __builtin_ctzll(m); m &= (m - 1);      \
                        const float4 w2 = wbuf[(p2 << 6) | lane];             \
                        if (m) {                                              \
                            const int p3 = __builtin_ctzll(m); m &= (m - 1);  \
                            const float4 w3 = wbuf[(p3 << 6) | lane];         \
                            LIF_ACC4(ACC[i], w0) LIF_ACC4(ACC[i], w1)         \
                            LIF_ACC4(ACC[i], w2) LIF_ACC4(ACC[i], w3)         \
                        } else {                                              \
                            LIF_ACC4(ACC[i], w0) LIF_ACC4(ACC[i], w1)         \
                            LIF_ACC4(ACC[i], w2)                              \
                        }                                                     \
                    } else { LIF_ACC4(ACC[i], w0) LIF_ACC4(ACC[i], w1) }      \
                } else { LIF_ACC4(ACC[i], w0) }                               \
            }                                                                 \
        }                                                                     \
    }

    #define LIF_CHUNK(C, ACC)                                                 \
        __syncthreads();                                                      \
        LIF_STAGE(C)                                                          \
        asm volatile("s_waitcnt vmcnt(0)" ::: "memory");                      \
        __syncthreads();                                                      \
        LIF_COMPUTE(C, ACC)

    LIF_CHUNK(0,  accA) LIF_CHUNK(1,  accA) LIF_CHUNK(2,  accA) LIF_CHUNK(3,  accA)
    LIF_CHUNK(4,  accA) LIF_CHUNK(5,  accA) LIF_CHUNK(6,  accA) LIF_CHUNK(7,  accA)
    LIF_CHUNK(8,  accB) LIF_CHUNK(9,  accB) LIF_CHUNK(10, accB) LIF_CHUNK(11, accB)
    LIF_CHUNK(12, accB) LIF_CHUNK(13, accB) LIF_CHUNK(14, accB) LIF_CHUNK(15, accB)

    #undef LIF_CHUNK
    #undef LIF_COMPUTE
    #undef LIF_STAGE
    #undef LIF_ACC4

    // epilogue: locked panel association P0 + P1, then store
    #pragma unroll
    for (int i = 0; i < 8; ++i) {
        float4 c4;
        c4.x = __fadd_rn(accA[i].x, accB[i].x);
        c4.y = __fadd_rn(accA[i].y, accB[i].y);
        c4.z = __fadd_rn(accA[i].z, accB[i].z);
        c4.w = __fadd_rn(accA[i].w, accB[i].w);
        const int row = row0 + (wave << 3) + i;
        *reinterpret_cast<float4*>(cur_out + (size_t)row * LIF_D + dbase + (lane << 2)) = c4;
    }
}

__global__ __launch_bounds__(256) void lif_scan_kernel(
    float* __restrict__ voltage,        // in: staged currents, out: v_new
    float* __restrict__ spikes_out)     // out: binary spikes
{
    const int tid = blockIdx.x * 256 + threadIdx.x;   // 0 .. B*D-1
    const int b = tid >> 10;
    const int d = tid & (LIF_D - 1);

    float v = 0.0f;
    const size_t base = ((size_t)b * LIF_T) * LIF_D + d;

    float p0 = voltage[base + 0 * (size_t)LIF_D];
    float p1 = voltage[base + 1 * (size_t)LIF_D];
    float p2 = voltage[base + 2 * (size_t)LIF_D];
    float p3 = voltage[base + 3 * (size_t)LIF_D];

    for (int t = 0; t < LIF_T; t += 4) {
        const float c0 = p0, c1 = p1, c2 = p2, c3 = p3;
        if (t + 4 < LIF_T) {
            p0 = voltage[base + (size_t)(t + 4) * LIF_D];
            p1 = voltage[base + (size_t)(t + 5) * LIF_D];
            p2 = voltage[base + (size_t)(t + 6) * LIF_D];
            p3 = voltage[base + (size_t)(t + 7) * LIF_D];
        }
        const size_t i0 = base + (size_t)t * LIF_D;
        {
            const float vn = __fadd_rn(__fmul_rn(0.9f, v), c0);
            const bool f = (vn >= 1.0f);
            voltage[i0 + 0 * (size_t)LIF_D] = vn;
            spikes_out[i0 + 0 * (size_t)LIF_D] = f ? 1.0f : 0.0f;
            v = f ? 0.0f : vn;
        }
        {
            const float vn = __fadd_rn(__fmul_rn(0.9f, v), c1);
            const bool f = (vn >= 1.0f);
            voltage[i0 + 1 * (size_t)LIF_D] = vn;
            spikes_out[i0 + 1 * (size_t)LIF_D] = f ? 1.0f : 0.0f;
            v = f ? 0.0f : vn;
        }
        {
            const float vn = __fadd_rn(__fmul_rn(0.9f, v), c2);
            const bool f = (vn >= 1.0f);
            voltage[i0 + 2 * (size_t)LIF_D] = vn;
            spikes_out[i0 + 2 * (size_t)LIF_D] = f ? 1.0f : 0.0f;
            v = f ? 0.0f : vn;
        }
        {
            const float vn = __fadd_rn(__fmul_rn(0.9f, v), c3);
            const bool f = (vn >= 1.0f);
            voltage[i0 + 3 * (size_t)LIF_D] = vn;
            spikes_out[i0 + 3 * (size_t)LIF_D] = f ? 1.0f : 0.0f;
            v = f ? 0.0f : vn;
        }
    }
}

extern "C" void kernel_launch(void* const* d_in, const int* in_sizes, int n_in,
                              void* d_out, int out_size, void* d_ws, size_t ws_size,
                              hipStream_t stream) {
    (void)in_sizes; (void)n_in; (void)out_size; (void)d_ws; (void)ws_size;

    // d_in[0] = prv_voltage (UNUSED by reference)
    const float* spikes = (const float*)d_in[1];   // (B,T,P) binary fp32
    const float* W      = (const float*)d_in[2];   // (P,D) fp32

    float* out        = (float*)d_out;
    float* voltage    = out;                       // N floats (stages currents)
    float* spikes_out = out + LIF_N;               // N floats

    lif_currents_kernel<<<2048, 256, 0, stream>>>(spikes, W, voltage);
    lif_scan_kernel<<<(LIF_B * LIF_D) / 256, 256, 0, stream>>>(voltage, spikes_out);
}